// Round 1
// baseline (181.470 us; speedup 1.0000x reference)
//
#include <hip/hip_runtime.h>
#include <math.h>

#define N_TRIAL 1000000
#define N_REF 8
#define N_DIM 16
#define BETA 1.0f
#define GAMMA 0.001f
// N_SELECT = {1,2,3,1} packed as nibbles: idx 0->1, 1->2, 2->3, 3->1
#define N_SELECT_PACKED 0x1321

__device__ __forceinline__ float wdist4(float4 w, float4 a, float4 b) {
    float dx = a.x - b.x, dy = a.y - b.y, dz = a.z - b.z, dw = a.w - b.w;
    return w.x * dx * dx + w.y * dy * dy + w.z * dz * dz + w.w * dw * dw;
}

__global__ __launch_bounds__(256) void likelihood_kernel(
    const int* __restrict__ stim,     // N_TRIAL x (N_REF+1)
    const int* __restrict__ config,   // N_TRIAL
    const int* __restrict__ group,    // N_TRIAL
    const int* __restrict__ present,  // N_TRIAL x (N_REF+1)
    const float* __restrict__ embed,  // N_STIM x N_DIM
    const float* __restrict__ attw,   // N_GROUP x N_DIM
    float* __restrict__ out)          // N_TRIAL
{
    int t = blockIdx.x * blockDim.x + threadIdx.x;
    if (t >= N_TRIAL) return;

    int g = group[t];
    int c = config[t];
    int ns = (N_SELECT_PACKED >> ((c & 3) * 4)) & 0xF;

    const float4* wp = (const float4*)(attw + g * N_DIM);
    float4 w0 = wp[0], w1 = wp[1], w2 = wp[2], w3 = wp[3];

    const int* sp = stim + t * (N_REF + 1);
    const int* pp = present + t * (N_REF + 1);

    int q = sp[0];
    const float4* zq = (const float4*)(embed + q * N_DIM);
    float4 q0 = zq[0], q1 = zq[1], q2 = zq[2], q3 = zq[3];

    float sim[N_REF];
#pragma unroll
    for (int r = 0; r < N_REF; ++r) {
        int s = sp[1 + r];
        const float4* zr = (const float4*)(embed + s * N_DIM);
        float4 r0 = zr[0], r1 = zr[1], r2 = zr[2], r3 = zr[3];
        float d = wdist4(w0, q0, r0) + wdist4(w1, q1, r1) +
                  wdist4(w2, q2, r2) + wdist4(w3, q3, r3);
        d = sqrtf(d);
        float s_qr = __expf(-BETA * d) + GAMMA;
        sim[r] = s_qr * (float)pp[1 + r];
    }

    // reverse (suffix) cumulative sum
    float suffix[N_REF];
    float acc = 0.0f;
#pragma unroll
    for (int r = N_REF - 1; r >= 0; --r) {
        acc += sim[r];
        suffix[r] = acc;
    }

    // product over masked positions (ns in {1,2,3}; predicated, no divergence)
    float lik = 1.0f;
#pragma unroll
    for (int r = 0; r < N_REF; ++r) {
        lik *= (r < ns) ? (sim[r] / suffix[r]) : 1.0f;
    }

    out[t] = lik;
}

extern "C" void kernel_launch(void* const* d_in, const int* in_sizes, int n_in,
                              void* d_out, int out_size, void* d_ws, size_t ws_size,
                              hipStream_t stream) {
    const int*   stim    = (const int*)d_in[0];
    const int*   config  = (const int*)d_in[1];
    const int*   group   = (const int*)d_in[2];
    const int*   present = (const int*)d_in[3];
    const float* embed   = (const float*)d_in[4];
    const float* attw    = (const float*)d_in[5];
    float*       out     = (float*)d_out;

    int blocks = (N_TRIAL + 255) / 256;
    likelihood_kernel<<<blocks, 256, 0, stream>>>(stim, config, group, present,
                                                  embed, attw, out);
}